// Round 3
// baseline (623.761 us; speedup 1.0000x reference)
//
#include <hip/hip_runtime.h>
#include <math.h>

// out = gelu( segment_mean(sem[src,0,:]) @ W )
// R5: (a) finalize rewritten as register-W outer product: W k-chunk lives in
// VGPRs (loaded from global, L1/L2-hot), 8 rows x 4 cols per thread, m via
// LDS broadcast b128. DS per FLOP drops ~3x; FMA floor 21us. LDS 32KB.
// (b) fill_csr: 4 edges/thread, 4 atomics in flight before dependent stores
// (latency-chain probe). (c) gather: 16-edge unroll, 8 float4 loads in flight.

#define SLOT 64

// ---------------------------------------------------------------------------
// Phase A: single atomic pass. Edge e -> slot (tgt, pos). 4 edges/thread.
__global__ __launch_bounds__(256) void fill_csr(const int* __restrict__ edges,
        int* __restrict__ cnt, int* __restrict__ csr, int n_edges) {
    int t = blockIdx.x * blockDim.x + threadIdx.x;
    int base = t * 4;
    if (base + 3 < n_edges) {
        int4 a = ((const int4*)edges)[t * 2];
        int4 b = ((const int4*)edges)[t * 2 + 1];
        int src[4] = {a.x, a.z, b.x, b.z};
        int tgt[4] = {a.y, a.w, b.y, b.w};
        int pos[4];
        #pragma unroll
        for (int i = 0; i < 4; i++) pos[i] = atomicAdd(&cnt[tgt[i]], 1);
        #pragma unroll
        for (int i = 0; i < 4; i++)
            if (pos[i] < SLOT) csr[(size_t)tgt[i] * SLOT + pos[i]] = src[i];
    } else if (base < n_edges) {
        for (int e = base; e < n_edges; e++) {
            int2 p = ((const int2*)edges)[e];
            int pos = atomicAdd(&cnt[p.y], 1);
            if (pos < SLOT) csr[(size_t)p.y * SLOT + pos] = p.x;
        }
    }
}

// ---------------------------------------------------------------------------
// Phase B: one wave per node; coalesced 64-index load; lower/upper 32-lane
// halves take even/odd edges (float4 lane covers full 512B row per pair).
// 16 edges per main iter = 8 independent row loads in flight.
__global__ __launch_bounds__(256) void gather_mean(
        const float* __restrict__ sem, const int* __restrict__ cnt,
        const int* __restrict__ csr, float* __restrict__ mean, int n) {
    int gid  = blockIdx.x * blockDim.x + threadIdx.x;
    int node = gid >> 6;
    int lane = gid & 63;
    if (node >= n) return;

    int deg = cnt[node];
    int m   = min(deg, SLOT);
    int sv  = (lane < m) ? csr[(size_t)node * SLOT + lane] : 0;

    const int half = lane >> 5;   // 0: even edges, 1: odd edges
    const int q    = lane & 31;   // float4 slot within the 128-float row

    float4 acc = make_float4(0.f, 0.f, 0.f, 0.f);

    int j = 0;
    for (; j + 16 <= m; j += 16) {
        int s[8];
        #pragma unroll
        for (int u = 0; u < 8; u++) s[u] = __shfl(sv, j + 2 * u + half);
        float4 v[8];
        #pragma unroll
        for (int u = 0; u < 8; u++)
            v[u] = ((const float4*)(sem + (size_t)s[u] * 512))[q];
        #pragma unroll
        for (int u = 0; u < 8; u++) {
            acc.x += v[u].x; acc.y += v[u].y; acc.z += v[u].z; acc.w += v[u].w;
        }
    }
    for (; j + 2 <= m; j += 2) {
        int s = __shfl(sv, j + half);
        float4 v = ((const float4*)(sem + (size_t)s * 512))[q];
        acc.x += v.x; acc.y += v.y; acc.z += v.z; acc.w += v.w;
    }
    if (j < m) {                       // single leftover edge: lower half only
        int s = __shfl(sv, j);
        if (half == 0) {
            float4 v = ((const float4*)(sem + (size_t)s * 512))[q];
            acc.x += v.x; acc.y += v.y; acc.z += v.z; acc.w += v.w;
        }
    }

    float4 oth;
    oth.x = __shfl(acc.x, (lane + 32) & 63);
    oth.y = __shfl(acc.y, (lane + 32) & 63);
    oth.z = __shfl(acc.z, (lane + 32) & 63);
    oth.w = __shfl(acc.w, (lane + 32) & 63);

    if (half == 0) {
        float inv = 1.0f / fmaxf((float)deg, 1.0f);
        float4 t = make_float4((acc.x + oth.x) * inv, (acc.y + oth.y) * inv,
                               (acc.z + oth.z) * inv, (acc.w + oth.w) * inv);
        ((float4*)(mean + (size_t)node * 128))[q] = t;
    }
}

// ---------------------------------------------------------------------------
// Phase C: io = gelu(io @ W), in place. Register-W outer product:
// thread (rb,cg) owns rows rb*8..rb*8+7 x cols 4cg..4cg+3 of a 64-row tile.
// Per k-chunk of 8: W[k0..k0+7][4cg] in 8 float4 VGPRs (global, L1-hot),
// m rows via 2 broadcast ds_read_b128. 1024 FMA lanes per 10 loads.
__device__ __forceinline__ float gelu_exact(float x) {
    return 0.5f * x * (1.0f + erff(x * 0.70710678118654752f));
}
__device__ __forceinline__ void fma4(float m, const float4 w, float4& a) {
    a.x = fmaf(m, w.x, a.x); a.y = fmaf(m, w.y, a.y);
    a.z = fmaf(m, w.z, a.z); a.w = fmaf(m, w.w, a.w);
}

__global__ __launch_bounds__(256) void finalize_kernel(
        const float* __restrict__ W, float* __restrict__ io, int n) {
    __shared__ float ml[64 * 128];     // 32 KB

    const int cg = threadIdx.x & 31;   // float4 col group
    const int rb = threadIdx.x >> 5;   // 0..7 -> rows rb*8 .. rb*8+7
    const int rowsPerIter = 64 * gridDim.x;

    for (int row0 = blockIdx.x * 64; row0 < n; row0 += rowsPerIter) {
        __syncthreads();   // prev-iter ml reads done
        #pragma unroll
        for (int p = 0; p < 8; p++) {
            int fid = threadIdx.x + 256 * p;      // 0..2047 float4 slots
            int rr = fid >> 5, k4 = fid & 31;
            int row = row0 + rr;
            if (row < n)
                ((float4*)ml)[fid] = ((const float4*)(io + (size_t)row * 128))[k4];
        }
        __syncthreads();

        float4 acc[8];
        #pragma unroll
        for (int i = 0; i < 8; i++) acc[i] = make_float4(0.f, 0.f, 0.f, 0.f);

        const float* mbase = ml + rb * 8 * 128;

        for (int kc = 0; kc < 16; kc++) {
            float4 wreg[8];
            #pragma unroll
            for (int u = 0; u < 8; u++)
                wreg[u] = ((const float4*)(W + (size_t)(kc * 8 + u) * 128))[cg];
            #pragma unroll
            for (int rr = 0; rr < 8; rr++) {
                const float4* mrow = (const float4*)(mbase + rr * 128);
                float4 mlo = mrow[kc * 2], mhi = mrow[kc * 2 + 1];
                fma4(mlo.x, wreg[0], acc[rr]);
                fma4(mlo.y, wreg[1], acc[rr]);
                fma4(mlo.z, wreg[2], acc[rr]);
                fma4(mlo.w, wreg[3], acc[rr]);
                fma4(mhi.x, wreg[4], acc[rr]);
                fma4(mhi.y, wreg[5], acc[rr]);
                fma4(mhi.z, wreg[6], acc[rr]);
                fma4(mhi.w, wreg[7], acc[rr]);
            }
        }

        #pragma unroll
        for (int rr = 0; rr < 8; rr++) {
            int row = row0 + rb * 8 + rr;
            if (row < n) {
                float4 g = make_float4(gelu_exact(acc[rr].x), gelu_exact(acc[rr].y),
                                       gelu_exact(acc[rr].z), gelu_exact(acc[rr].w));
                ((float4*)(io + (size_t)row * 128))[cg] = g;
            }
        }
    }
}

// ---------------------------------------------------------------------------
extern "C" void kernel_launch(void* const* d_in, const int* in_sizes, int n_in,
                              void* d_out, int out_size, void* d_ws, size_t ws_size,
                              hipStream_t stream) {
    const float* sem   = (const float*)d_in[0];
    const float* W     = (const float*)d_in[2];
    const int*   edges = (const int*)d_in[3];

    const int n       = in_sizes[0] / (4 * 128);  // 100000
    const int n_edges = in_sizes[3] / 2;          // 1600000

    // ws layout: cnt (n ints, 400KB) | csr (n*64 ints, 25.6MB)
    char* p = (char*)d_ws;
    int* cnt = (int*)p;   p += (((size_t)n * 4) + 15) & ~(size_t)15;
    int* csr = (int*)p;

    hipMemsetAsync(cnt, 0, (size_t)n * 4, stream);

    const int T = 256;
    const int fthreads = (n_edges + 3) / 4;
    fill_csr   <<<(fthreads + T - 1) / T, T, 0, stream>>>(edges, cnt, csr, n_edges);

    const int gblocks = (int)(((long long)n * 64 + T - 1) / T);  // 25000
    gather_mean<<<gblocks, T, 0, stream>>>(sem, cnt, csr, (float*)d_out, n);

    finalize_kernel<<<1024, T, 0, stream>>>(W, (float*)d_out, n);
}

// Round 4
// 598.108 us; speedup vs baseline: 1.0429x; 1.0429x over previous
//
#include <hip/hip_runtime.h>
#include <math.h>

// out = gelu( segment_mean(sem[src,0,:]) @ W )
// R6: re-anchor to best-known config after R5's -42us multi-change regression.
// - fill_csr: 1 edge/thread (proven 124us; phase is atomic-throughput-bound
//   ~13G atomics/s at the coherence point — R2 hist==build_csr==124us proves
//   scatter rides free; per-thread ILP (R5) only cut occupancy, 143us).
// - gather: R5's 16-edge unroll (deg~Poisson(16) -> one main iter, 8 row
//   loads in flight; at L2-capacity-miss ceiling ~3.6TB/s, 378MB traffic).
// - finalize: R4's proven W-in-LDS 32-row 4x4 register-blocked version.

#define SLOT 64

// ---------------------------------------------------------------------------
// Phase A: single atomic pass. Edge e -> slot (tgt, pos).
__global__ void fill_csr(const int* __restrict__ edges, int* __restrict__ cnt,
                         int* __restrict__ csr, int n_edges) {
    int e = blockIdx.x * blockDim.x + threadIdx.x;
    if (e < n_edges) {
        int2 p = ((const int2*)edges)[e];
        int pos = atomicAdd(&cnt[p.y], 1);
        if (pos < SLOT) csr[(size_t)p.y * SLOT + pos] = p.x;
    }
}

// ---------------------------------------------------------------------------
// Phase B: one wave per node; coalesced 64-index load; lower/upper 32-lane
// halves take even/odd edges (float4 lane covers full 512B row per pair).
// 16 edges per main iter = 8 independent row loads in flight.
__global__ __launch_bounds__(256) void gather_mean(
        const float* __restrict__ sem, const int* __restrict__ cnt,
        const int* __restrict__ csr, float* __restrict__ mean, int n) {
    int gid  = blockIdx.x * blockDim.x + threadIdx.x;
    int node = gid >> 6;
    int lane = gid & 63;
    if (node >= n) return;

    int deg = cnt[node];
    int m   = min(deg, SLOT);
    int sv  = (lane < m) ? csr[(size_t)node * SLOT + lane] : 0;

    const int half = lane >> 5;   // 0: even edges, 1: odd edges
    const int q    = lane & 31;   // float4 slot within the 128-float row

    float4 acc = make_float4(0.f, 0.f, 0.f, 0.f);

    int j = 0;
    for (; j + 16 <= m; j += 16) {
        int s[8];
        #pragma unroll
        for (int u = 0; u < 8; u++) s[u] = __shfl(sv, j + 2 * u + half);
        float4 v[8];
        #pragma unroll
        for (int u = 0; u < 8; u++)
            v[u] = ((const float4*)(sem + (size_t)s[u] * 512))[q];
        #pragma unroll
        for (int u = 0; u < 8; u++) {
            acc.x += v[u].x; acc.y += v[u].y; acc.z += v[u].z; acc.w += v[u].w;
        }
    }
    for (; j + 2 <= m; j += 2) {
        int s = __shfl(sv, j + half);
        float4 v = ((const float4*)(sem + (size_t)s * 512))[q];
        acc.x += v.x; acc.y += v.y; acc.z += v.z; acc.w += v.w;
    }
    if (j < m) {                       // single leftover edge: lower half only
        int s = __shfl(sv, j);
        if (half == 0) {
            float4 v = ((const float4*)(sem + (size_t)s * 512))[q];
            acc.x += v.x; acc.y += v.y; acc.z += v.z; acc.w += v.w;
        }
    }

    float4 oth;
    oth.x = __shfl(acc.x, (lane + 32) & 63);
    oth.y = __shfl(acc.y, (lane + 32) & 63);
    oth.z = __shfl(acc.z, (lane + 32) & 63);
    oth.w = __shfl(acc.w, (lane + 32) & 63);

    if (half == 0) {
        float inv = 1.0f / fmaxf((float)deg, 1.0f);
        float4 t = make_float4((acc.x + oth.x) * inv, (acc.y + oth.y) * inv,
                               (acc.z + oth.z) * inv, (acc.w + oth.w) * inv);
        ((float4*)(mean + (size_t)node * 128))[q] = t;
    }
}

// ---------------------------------------------------------------------------
// Phase C: io = gelu(io @ W), in place. 4 rows x 4 cols per thread
// (32 rows/iter), W staged once in LDS, m-row reads are float4 broadcasts.
__device__ __forceinline__ float gelu_exact(float x) {
    return 0.5f * x * (1.0f + erff(x * 0.70710678118654752f));
}
__device__ __forceinline__ void fma4(float m, const float4 w, float4& a) {
    a.x = fmaf(m, w.x, a.x); a.y = fmaf(m, w.y, a.y);
    a.z = fmaf(m, w.z, a.z); a.w = fmaf(m, w.w, a.w);
}

__global__ __launch_bounds__(256, 2) void finalize_kernel(
        const float* __restrict__ W, float* __restrict__ io, int n) {
    __shared__ float Wl[128 * 128];   // 64 KB
    __shared__ float ml[32 * 128];    // 16 KB -> 80 KB total, 2 blocks/CU

    for (int i = threadIdx.x; i < 128 * 32; i += 256)
        ((float4*)Wl)[i] = ((const float4*)W)[i];

    const int r  = threadIdx.x >> 5;   // 0..7 -> rows r, r+8, r+16, r+24
    const int cg = threadIdx.x & 31;   // float4 col group
    const int rowsPerIter = 32 * gridDim.x;

    for (int row0 = blockIdx.x * 32; row0 < n; row0 += rowsPerIter) {
        __syncthreads();  // Wl ready (iter 0) / prev ml reads + stores done
        #pragma unroll
        for (int p = 0; p < 4; p++) {
            int fid = threadIdx.x + 256 * p;   // 0..1023 float4 slots of ml
            int rr = fid >> 5, k4 = fid & 31;
            int row = row0 + rr;
            if (row < n)
                ((float4*)ml)[fid] = ((const float4*)(io + (size_t)row * 128))[k4];
        }
        __syncthreads();

        float4 a0, a1, a2, a3;
        a0 = a1 = a2 = a3 = make_float4(0.f, 0.f, 0.f, 0.f);
        const float4* m0 = (const float4*)(ml + (r     ) * 128);
        const float4* m1 = (const float4*)(ml + (r +  8) * 128);
        const float4* m2 = (const float4*)(ml + (r + 16) * 128);
        const float4* m3 = (const float4*)(ml + (r + 24) * 128);

        #pragma unroll 2
        for (int k4 = 0; k4 < 32; k4++) {
            float4 mv0 = m0[k4], mv1 = m1[k4], mv2 = m2[k4], mv3 = m3[k4];
            const float* p0 = (const float*)&mv0;
            const float* p1 = (const float*)&mv1;
            const float* p2 = (const float*)&mv2;
            const float* p3 = (const float*)&mv3;
            #pragma unroll
            for (int kk = 0; kk < 4; kk++) {
                float4 wv = ((const float4*)(Wl + (k4 * 4 + kk) * 128))[cg];
                fma4(p0[kk], wv, a0);
                fma4(p1[kk], wv, a1);
                fma4(p2[kk], wv, a2);
                fma4(p3[kk], wv, a3);
            }
        }

        int rowA = row0 + r;
        if (rowA < n) {
            float4 g = make_float4(gelu_exact(a0.x), gelu_exact(a0.y),
                                   gelu_exact(a0.z), gelu_exact(a0.w));
            ((float4*)(io + (size_t)rowA * 128))[cg] = g;
        }
        int rowB = row0 + r + 8;
        if (rowB < n) {
            float4 g = make_float4(gelu_exact(a1.x), gelu_exact(a1.y),
                                   gelu_exact(a1.z), gelu_exact(a1.w));
            ((float4*)(io + (size_t)rowB * 128))[cg] = g;
        }
        int rowC = row0 + r + 16;
        if (rowC < n) {
            float4 g = make_float4(gelu_exact(a2.x), gelu_exact(a2.y),
                                   gelu_exact(a2.z), gelu_exact(a2.w));
            ((float4*)(io + (size_t)rowC * 128))[cg] = g;
        }
        int rowD = row0 + r + 24;
        if (rowD < n) {
            float4 g = make_float4(gelu_exact(a3.x), gelu_exact(a3.y),
                                   gelu_exact(a3.z), gelu_exact(a3.w));
            ((float4*)(io + (size_t)rowD * 128))[cg] = g;
        }
    }
}

// ---------------------------------------------------------------------------
extern "C" void kernel_launch(void* const* d_in, const int* in_sizes, int n_in,
                              void* d_out, int out_size, void* d_ws, size_t ws_size,
                              hipStream_t stream) {
    const float* sem   = (const float*)d_in[0];
    const float* W     = (const float*)d_in[2];
    const int*   edges = (const int*)d_in[3];

    const int n       = in_sizes[0] / (4 * 128);  // 100000
    const int n_edges = in_sizes[3] / 2;          // 1600000

    // ws layout: cnt (n ints, 400KB) | csr (n*64 ints, 25.6MB)
    char* p = (char*)d_ws;
    int* cnt = (int*)p;   p += (((size_t)n * 4) + 15) & ~(size_t)15;
    int* csr = (int*)p;

    hipMemsetAsync(cnt, 0, (size_t)n * 4, stream);

    const int T = 256;
    fill_csr   <<<(n_edges + T - 1) / T, T, 0, stream>>>(edges, cnt, csr, n_edges);

    const int gblocks = (int)(((long long)n * 64 + T - 1) / T);  // 25000
    gather_mean<<<gblocks, T, 0, stream>>>(sem, cnt, csr, (float*)d_out, n);

    finalize_kernel<<<512,  T, 0, stream>>>(W, (float*)d_out, n);
}

// Round 5
// 553.862 us; speedup vs baseline: 1.1262x; 1.0799x over previous
//
#include <hip/hip_runtime.h>
#include <math.h>

// out = gelu( segment_mean(sem[src,0,:] @ W) )     [linear => == mean then @W]
// R7: exploit that fill_csr's 124us atomic wall leaves the GPU empty
// (VALUBusy 0.26%, HBM 9%). W commutes with segment-mean, so compute
// h = sem[:,0] @ W in a fused kernel grid-partitioned with the CSR fill
// (1:6 block interleave; matmul = reg-W outer product, 32KB LDS so fill
// keeps ~16-20 waves/CU). Gather reads h (same random-512B pattern) and
// applies gelu in-register -> standalone finalize kernel deleted.

#define SLOT 64

__device__ __forceinline__ float gelu_exact(float x) {
    return 0.5f * x * (1.0f + erff(x * 0.70710678118654752f));
}
__device__ __forceinline__ void fma4(float m, const float4 w, float4& a) {
    a.x = fmaf(m, w.x, a.x); a.y = fmaf(m, w.y, a.y);
    a.z = fmaf(m, w.z, a.z); a.w = fmaf(m, w.w, a.w);
}

// ---------------------------------------------------------------------------
// Phase A (fused): role by blockIdx. bid%7==0 -> matmul block, else fill block.
// Fill: 1 edge/thread, single returning atomic (proven 124us wall config).
// Matmul: 64-row tile in LDS, thread (rb,cg) owns 8 rows x 4 cols; W k-chunk
// of 8 rows lives in 8 float4 VGPRs loaded from global (64KB W is L2-hot).
__global__ __launch_bounds__(256) void fill_and_matmul(
        const int* __restrict__ edges, int* __restrict__ cnt,
        int* __restrict__ csr, int n_edges,
        const float* __restrict__ sem, const float* __restrict__ W,
        float* __restrict__ h, int n, int mm_blocks) {
    __shared__ float ml[64 * 128];     // 32 KB (matmul role only)

    int bid = blockIdx.x;
    if (bid % 7 != 0) {
        // ---- fill role ----
        int fb = bid - bid / 7 - 1;                 // 0..FB-1, dense
        int e  = fb * 256 + (int)threadIdx.x;
        if (e < n_edges) {
            int2 p = ((const int2*)edges)[e];
            int pos = atomicAdd(&cnt[p.y], 1);
            if (pos < SLOT) csr[(size_t)p.y * SLOT + pos] = p.x;
        }
        return;
    }

    // ---- matmul role: h[row] = sem[row,0,:] @ W ----
    int mb = bid / 7;                               // 0..mm_blocks-1
    const int cg = threadIdx.x & 31;                // float4 col group
    const int rb = threadIdx.x >> 5;                // 0..7 -> rows rb*8..rb*8+7
    const int rowsPerIter = 64 * mm_blocks;

    for (int row0 = mb * 64; row0 < n; row0 += rowsPerIter) {
        __syncthreads();   // prev-iter ml reads done
        #pragma unroll
        for (int p = 0; p < 8; p++) {
            int fid = threadIdx.x + 256 * p;        // 0..2047 float4 slots
            int rr = fid >> 5, k4 = fid & 31;
            int row = row0 + rr;
            if (row < n)   // sem row stride = 4*128 floats; seq_len slot 0
                ((float4*)ml)[fid] = ((const float4*)(sem + (size_t)row * 512))[k4];
        }
        __syncthreads();

        float4 acc[8];
        #pragma unroll
        for (int i = 0; i < 8; i++) acc[i] = make_float4(0.f, 0.f, 0.f, 0.f);

        const float* mbase = ml + rb * 8 * 128;

        for (int kc = 0; kc < 16; kc++) {
            float4 wreg[8];
            #pragma unroll
            for (int u = 0; u < 8; u++)
                wreg[u] = ((const float4*)(W + (size_t)(kc * 8 + u) * 128))[cg];
            #pragma unroll
            for (int rr = 0; rr < 8; rr++) {
                const float4* mrow = (const float4*)(mbase + rr * 128);
                float4 mlo = mrow[kc * 2], mhi = mrow[kc * 2 + 1];
                fma4(mlo.x, wreg[0], acc[rr]);
                fma4(mlo.y, wreg[1], acc[rr]);
                fma4(mlo.z, wreg[2], acc[rr]);
                fma4(mlo.w, wreg[3], acc[rr]);
                fma4(mhi.x, wreg[4], acc[rr]);
                fma4(mhi.y, wreg[5], acc[rr]);
                fma4(mhi.z, wreg[6], acc[rr]);
                fma4(mhi.w, wreg[7], acc[rr]);
            }
        }

        #pragma unroll
        for (int rr = 0; rr < 8; rr++) {
            int row = row0 + rb * 8 + rr;
            if (row < n)
                ((float4*)(h + (size_t)row * 128))[cg] = acc[rr];
        }
    }
}

// ---------------------------------------------------------------------------
// Phase B: one wave per node; coalesced 64-index load; lower/upper 32-lane
// halves take even/odd edges (float4 lane covers full 512B h row per pair).
// 16 edges per main iter = 8 independent row loads in flight. Gelu fused.
__global__ __launch_bounds__(256) void gather_gelu(
        const float* __restrict__ h, const int* __restrict__ cnt,
        const int* __restrict__ csr, float* __restrict__ out, int n) {
    int gid  = blockIdx.x * blockDim.x + threadIdx.x;
    int node = gid >> 6;
    int lane = gid & 63;
    if (node >= n) return;

    int deg = cnt[node];
    int m   = min(deg, SLOT);
    int sv  = (lane < m) ? csr[(size_t)node * SLOT + lane] : 0;

    const int half = lane >> 5;   // 0: even edges, 1: odd edges
    const int q    = lane & 31;   // float4 slot within the 128-float row

    float4 acc = make_float4(0.f, 0.f, 0.f, 0.f);

    int j = 0;
    for (; j + 16 <= m; j += 16) {
        int s[8];
        #pragma unroll
        for (int u = 0; u < 8; u++) s[u] = __shfl(sv, j + 2 * u + half);
        float4 v[8];
        #pragma unroll
        for (int u = 0; u < 8; u++)
            v[u] = ((const float4*)(h + (size_t)s[u] * 128))[q];
        #pragma unroll
        for (int u = 0; u < 8; u++) {
            acc.x += v[u].x; acc.y += v[u].y; acc.z += v[u].z; acc.w += v[u].w;
        }
    }
    for (; j + 2 <= m; j += 2) {
        int s = __shfl(sv, j + half);
        float4 v = ((const float4*)(h + (size_t)s * 128))[q];
        acc.x += v.x; acc.y += v.y; acc.z += v.z; acc.w += v.w;
    }
    if (j < m) {                       // single leftover edge: lower half only
        int s = __shfl(sv, j);
        if (half == 0) {
            float4 v = ((const float4*)(h + (size_t)s * 128))[q];
            acc.x += v.x; acc.y += v.y; acc.z += v.z; acc.w += v.w;
        }
    }

    float4 oth;
    oth.x = __shfl(acc.x, (lane + 32) & 63);
    oth.y = __shfl(acc.y, (lane + 32) & 63);
    oth.z = __shfl(acc.z, (lane + 32) & 63);
    oth.w = __shfl(acc.w, (lane + 32) & 63);

    if (half == 0) {
        float inv = 1.0f / fmaxf((float)deg, 1.0f);
        float4 t = make_float4(gelu_exact((acc.x + oth.x) * inv),
                               gelu_exact((acc.y + oth.y) * inv),
                               gelu_exact((acc.z + oth.z) * inv),
                               gelu_exact((acc.w + oth.w) * inv));
        ((float4*)(out + (size_t)node * 128))[q] = t;
    }
}

// ---------------------------------------------------------------------------
extern "C" void kernel_launch(void* const* d_in, const int* in_sizes, int n_in,
                              void* d_out, int out_size, void* d_ws, size_t ws_size,
                              hipStream_t stream) {
    const float* sem   = (const float*)d_in[0];
    const float* W     = (const float*)d_in[2];
    const int*   edges = (const int*)d_in[3];

    const int n       = in_sizes[0] / (4 * 128);  // 100000
    const int n_edges = in_sizes[3] / 2;          // 1600000

    // ws layout: cnt (n ints) | csr (n*64 ints) | h (n*128 floats)  ~77 MB
    auto align16 = [](size_t x) { return (x + 15) & ~(size_t)15; };
    char* p = (char*)d_ws;
    int*   cnt = (int*)p;    p += align16((size_t)n * 4);
    int*   csr = (int*)p;    p += align16((size_t)n * SLOT * 4);
    float* h   = (float*)p;

    hipMemsetAsync(cnt, 0, (size_t)n * 4, stream);

    const int T  = 256;
    const int FB = (n_edges + T - 1) / T;          // 6250 fill blocks
    // interleave 1:6 -> total T_b with ceil(T_b/7) matmul blocks, FB fill
    const int total = (FB * 7 + 5) / 6;            // 7292
    const int MB    = total - FB;                  // 1042 matmul blocks

    fill_and_matmul<<<total, T, 0, stream>>>(edges, cnt, csr, n_edges,
                                             sem, W, h, n, MB);

    const int gblocks = (int)(((long long)n * 64 + T - 1) / T);  // 25000
    gather_gelu<<<gblocks, T, 0, stream>>>(h, cnt, csr, (float*)d_out, n);
}